// Round 1
// baseline (315.276 us; speedup 1.0000x reference)
//
#include <hip/hip_runtime.h>

// out[i] = sum_j softmax_j( -(x-s_j)^2 / T ) * s_j,  s = {-1,-0.5,0.5,1}, T=0.3
// Memory-bound elementwise: float4 vectorized, one thread per 4 elements.

#define C_EXP2 4.8089834696f   // (1/0.3) * log2(e)

__device__ __forceinline__ float quant1(float x) {
    // squared distances to the 4 states
    float d0 = (x + 1.0f) * (x + 1.0f);
    float d1 = (x + 0.5f) * (x + 0.5f);
    float d2 = (x - 0.5f) * (x - 0.5f);
    float d3 = (x - 1.0f) * (x - 1.0f);
    float m  = fminf(fminf(d0, d1), fminf(d2, d3));
    // softmax with max-logit subtracted: args <= 0, exp2 via v_exp_f32
    float w0 = __builtin_amdgcn_exp2f((m - d0) * C_EXP2);
    float w1 = __builtin_amdgcn_exp2f((m - d1) * C_EXP2);
    float w2 = __builtin_amdgcn_exp2f((m - d2) * C_EXP2);
    float w3 = __builtin_amdgcn_exp2f((m - d3) * C_EXP2);
    // num = -1*w0 -0.5*w1 +0.5*w2 +1*w3 = (w3-w0) + 0.5*(w2-w1)
    float num = (w3 - w0) + 0.5f * (w2 - w1);
    float den = (w0 + w1) + (w2 + w3);      // in [1,4]
    return num * __builtin_amdgcn_rcpf(den);
}

__global__ void __launch_bounds__(256)
FourStateQuantizer_42245298323776_kernel(const float4* __restrict__ x,
                                         float4* __restrict__ out, int n4) {
    int i = blockIdx.x * blockDim.x + threadIdx.x;
    if (i < n4) {
        float4 v = x[i];
        float4 r;
        r.x = quant1(v.x);
        r.y = quant1(v.y);
        r.z = quant1(v.z);
        r.w = quant1(v.w);
        out[i] = r;
    }
}

extern "C" void kernel_launch(void* const* d_in, const int* in_sizes, int n_in,
                              void* d_out, int out_size, void* d_ws, size_t ws_size,
                              hipStream_t stream) {
    const float4* x = (const float4*)d_in[0];
    float4* out = (float4*)d_out;
    int n = in_sizes[0];          // 50331648 total floats
    int n4 = n >> 2;              // divisible by 4
    int block = 256;
    int grid = (n4 + block - 1) / block;
    FourStateQuantizer_42245298323776_kernel<<<grid, block, 0, stream>>>(x, out, n4);
}

// Round 3
// 313.149 us; speedup vs baseline: 1.0068x; 1.0068x over previous
//
#include <hip/hip_runtime.h>

// out[i] = sum_j softmax_j( -(x-s_j)^2 / T ) * s_j,  s = {-1,-0.5,0.5,1}, T=0.3
// Memory-bound elementwise: float4 vectorized + nontemporal streaming hints
// (input read-once, output write-once -> bypass L2 allocate where possible).
// NOTE: nontemporal builtins need native clang vector types, not HIP_vector_type.

typedef float f4 __attribute__((ext_vector_type(4)));

#define C_EXP2 4.8089834696f   // (1/0.3) * log2(e)

__device__ __forceinline__ float quant1(float x) {
    float d0 = (x + 1.0f) * (x + 1.0f);
    float d1 = (x + 0.5f) * (x + 0.5f);
    float d2 = (x - 0.5f) * (x - 0.5f);
    float d3 = (x - 1.0f) * (x - 1.0f);
    float m  = fminf(fminf(d0, d1), fminf(d2, d3));
    // softmax with min-dist subtracted: args <= 0, exp2 via v_exp_f32
    float w0 = __builtin_amdgcn_exp2f((m - d0) * C_EXP2);
    float w1 = __builtin_amdgcn_exp2f((m - d1) * C_EXP2);
    float w2 = __builtin_amdgcn_exp2f((m - d2) * C_EXP2);
    float w3 = __builtin_amdgcn_exp2f((m - d3) * C_EXP2);
    float num = (w3 - w0) + 0.5f * (w2 - w1);
    float den = (w0 + w1) + (w2 + w3);      // in [1,4]
    return num * __builtin_amdgcn_rcpf(den);
}

__global__ void __launch_bounds__(256)
FourStateQuantizer_42245298323776_kernel(const f4* __restrict__ x,
                                         f4* __restrict__ out, int n4) {
    int i = blockIdx.x * blockDim.x + threadIdx.x;
    if (i < n4) {
        f4 v = __builtin_nontemporal_load(&x[i]);
        f4 r;
        r.x = quant1(v.x);
        r.y = quant1(v.y);
        r.z = quant1(v.z);
        r.w = quant1(v.w);
        __builtin_nontemporal_store(r, &out[i]);
    }
}

extern "C" void kernel_launch(void* const* d_in, const int* in_sizes, int n_in,
                              void* d_out, int out_size, void* d_ws, size_t ws_size,
                              hipStream_t stream) {
    const f4* x = (const f4*)d_in[0];
    f4* out = (f4*)d_out;
    int n = in_sizes[0];          // 50331648 total floats
    int n4 = n >> 2;              // divisible by 4
    int block = 256;
    int grid = (n4 + block - 1) / block;
    FourStateQuantizer_42245298323776_kernel<<<grid, block, 0, stream>>>(x, out, n4);
}